// Round 3
// baseline (4302.774 us; speedup 1.0000x reference)
//
#include <hip/hip_runtime.h>
#include <hip/hip_bf16.h>
#include <stdint.h>

#define T 2048
#define H 1024
#define F 512
#define E 32
#define KSEL 4
#define TM 16

typedef __hip_bfloat16 bf16;

union V8 { uint4 u4; unsigned short s[8]; };

__device__ __forceinline__ float b2f(unsigned short u) {
    union { unsigned u32; float f; } c; c.u32 = ((unsigned)u) << 16; return c.f;
}
__device__ __forceinline__ unsigned short f2b(float f) {
    bf16 b = __float2bfloat16(f);
    return *reinterpret_cast<unsigned short*>(&b);
}
// load 8 consecutive fp32 (k % 8 == 0, p 16B-aligned)
__device__ __forceinline__ void ld8f(const float* __restrict__ p, int k, float* o) {
    float4 a = *(const float4*)(p + k);
    float4 b = *(const float4*)(p + k + 4);
    o[0] = a.x; o[1] = a.y; o[2] = a.z; o[3] = a.w;
    o[4] = b.x; o[5] = b.y; o[6] = b.z; o[7] = b.w;
}

// ---------------- Router: fp32 logits out, top-4 softmax, per-expert token lists ----------------
__global__ __launch_bounds__(64) void k_router(const float* __restrict__ ri,
                                               const float* __restrict__ wr,
                                               float* __restrict__ logits_out,
                                               int* __restrict__ counts,
                                               uint2* __restrict__ entries) {
    __shared__ float lg[E];
    int t = blockIdx.x;
    int lane = threadIdx.x;
    int e = lane >> 1, half = lane & 1;
    const float4* x = (const float4*)(ri + (size_t)t * H + half * 512);
    const float4* w = (const float4*)(wr + (size_t)e * H + half * 512);
    float acc = 0.f;
    for (int i = 0; i < 128; ++i) {
        float4 xv = x[i], wv = w[i];
        acc += xv.x * wv.x + xv.y * wv.y + xv.z * wv.z + xv.w * wv.w;
    }
    acc += __shfl_xor(acc, 1, 64);
    if (half == 0) lg[e] = acc;
    __syncthreads();
    if (lane < E) logits_out[(size_t)t * E + lane] = lg[lane];
    if (lane == 0) {
        int sel[KSEL]; float val[KSEL];
        unsigned taken = 0;
        for (int k = 0; k < KSEL; ++k) {
            float best = -1e30f; int bi = 0;
            for (int i = 0; i < E; ++i)
                if (!((taken >> i) & 1u) && lg[i] > best) { best = lg[i]; bi = i; }
            taken |= 1u << bi; sel[k] = bi; val[k] = best;
        }
        float m = val[0], s = 0.f, w4[KSEL];
        for (int k = 0; k < KSEL; ++k) { w4[k] = __expf(val[k] - m); s += w4[k]; }
        float inv = 1.f / s;
        for (int k = 0; k < KSEL; ++k) {
            int pos = atomicAdd(&counts[sel[k]], 1);
            uint2 ent; ent.x = (unsigned)t; ent.y = __float_as_uint(w4[k] * inv);
            entries[(size_t)sel[k] * T + pos] = ent;
        }
    }
}

// ---------------- Expert FFN: gathered 16-token tiles, atomicAdd into fp32 out ----------------
__global__ __launch_bounds__(256) void k_expert(const float* __restrict__ hs,
                                                const float* __restrict__ wg,
                                                const float* __restrict__ wu,
                                                const float* __restrict__ wd,
                                                const int* __restrict__ counts,
                                                const uint2* __restrict__ entries,
                                                float* __restrict__ out) {
    int e = blockIdx.x;
    int tile = blockIdx.y;
    int n_tok = counts[e];
    int base = tile * TM;
    if (base >= n_tok) return;
    int rows = min(TM, n_tok - base);

    __shared__ unsigned short Xs[TM][H + 8];   // bf16 X tile
    __shared__ unsigned short H1s[TM][F + 8];  // bf16 intermediate
    __shared__ int tok_s[TM];
    __shared__ float wgt_s[TM];

    int tid = threadIdx.x;
    if (tid < TM) {
        uint2 ent = entries[(size_t)e * T + base + min(tid, rows - 1)];
        tok_s[tid] = (int)ent.x;
        wgt_s[tid] = (tid < rows) ? __uint_as_float(ent.y) : 0.f;
    }
    __syncthreads();
    // stage X tile (fp32 -> bf16 in LDS): 16 threads per row, 64 elements each
    {
        int m = tid >> 4, part = tid & 15;
        const float* src = hs + (size_t)tok_s[m] * H + part * 64;
#pragma unroll
        for (int j = 0; j < 8; ++j) {
            float4 v0 = *(const float4*)(src + j * 8);
            float4 v1 = *(const float4*)(src + j * 8 + 4);
            V8 o;
            o.s[0] = f2b(v0.x); o.s[1] = f2b(v0.y); o.s[2] = f2b(v0.z); o.s[3] = f2b(v0.w);
            o.s[4] = f2b(v1.x); o.s[5] = f2b(v1.y); o.s[6] = f2b(v1.z); o.s[7] = f2b(v1.w);
            *(uint4*)&Xs[m][part * 64 + j * 8] = o.u4;
        }
    }
    __syncthreads();

    int mg = tid >> 5;      // 8 row-groups of 2 rows
    int fg = tid & 31;      // 32 col-groups of 2 cols
    int m0 = mg * 2, m1 = m0 + 1;

    // Phase A: G/U = X*Wg^T, X*Wu^T ; H1 = relu(G)*U (bf16 to LDS)
    for (int ft = 0; ft < F / 64; ++ft) {
        int f0 = ft * 64 + fg * 2;
        const float* pg0 = wg + (size_t)e * F * H + (size_t)f0 * H;
        const float* pg1 = pg0 + H;
        const float* pu0 = wu + (size_t)e * F * H + (size_t)f0 * H;
        const float* pu1 = pu0 + H;
        float g0 = 0, g1 = 0, g2 = 0, g3 = 0, u0 = 0, u1 = 0, u2 = 0, u3 = 0;
        for (int k = 0; k < H; k += 8) {
            V8 xa, xb;
            xa.u4 = *(const uint4*)&Xs[m0][k];
            xb.u4 = *(const uint4*)&Xs[m1][k];
            float A0[8], A1[8], U0[8], U1[8];
            ld8f(pg0, k, A0); ld8f(pg1, k, A1);
            ld8f(pu0, k, U0); ld8f(pu1, k, U1);
#pragma unroll
            for (int j = 0; j < 8; ++j) {
                float xj0 = b2f(xa.s[j]), xj1 = b2f(xb.s[j]);
                g0 += xj0 * A0[j]; g1 += xj0 * A1[j]; g2 += xj1 * A0[j]; g3 += xj1 * A1[j];
                u0 += xj0 * U0[j]; u1 += xj0 * U1[j]; u2 += xj1 * U0[j]; u3 += xj1 * U1[j];
            }
        }
        H1s[m0][f0]     = f2b(fmaxf(g0, 0.f) * u0);
        H1s[m0][f0 + 1] = f2b(fmaxf(g1, 0.f) * u1);
        H1s[m1][f0]     = f2b(fmaxf(g2, 0.f) * u2);
        H1s[m1][f0 + 1] = f2b(fmaxf(g3, 0.f) * u3);
    }
    __syncthreads();

    // Phase B: Y = H1 * Wd^T, scaled by routing weight, atomicAdd into fp32 out
    float wm0 = wgt_s[m0], wm1 = wgt_s[m1];
    for (int nt = 0; nt < H / 64; ++nt) {
        int n0 = nt * 64 + fg * 2;
        const float* pd0 = wd + (size_t)e * H * F + (size_t)n0 * F;
        const float* pd1 = pd0 + F;
        float y00 = 0, y01 = 0, y10 = 0, y11 = 0;
        for (int f = 0; f < F; f += 8) {
            V8 ha, hb;
            ha.u4 = *(const uint4*)&H1s[m0][f];
            hb.u4 = *(const uint4*)&H1s[m1][f];
            float D0[8], D1[8];
            ld8f(pd0, f, D0); ld8f(pd1, f, D1);
#pragma unroll
            for (int j = 0; j < 8; ++j) {
                float h0 = b2f(ha.s[j]), h1 = b2f(hb.s[j]);
                y00 += h0 * D0[j]; y01 += h0 * D1[j]; y10 += h1 * D0[j]; y11 += h1 * D1[j];
            }
        }
        if (m0 < rows) {
            float* p = out + (size_t)tok_s[m0] * H + n0;
            atomicAdd(p, y00 * wm0); atomicAdd(p + 1, y01 * wm0);
        }
        if (m1 < rows) {
            float* p = out + (size_t)tok_s[m1] * H + n0;
            atomicAdd(p, y10 * wm1); atomicAdd(p + 1, y11 * wm1);
        }
    }
}

// ---------------- Fallback (tiny ws): one block per token, zero scratch ----------------
__global__ __launch_bounds__(256) void k_fallback(const float* __restrict__ ri,
                                                  const float* __restrict__ hs,
                                                  const float* __restrict__ wr,
                                                  const float* __restrict__ wg,
                                                  const float* __restrict__ wu,
                                                  const float* __restrict__ wd,
                                                  float* __restrict__ out) {
    __shared__ float lg[E];
    __shared__ float xs[H];
    __shared__ float hbuf[F];
    __shared__ float obuf[H];
    __shared__ float sel_w[KSEL];
    __shared__ int sel_e[KSEL];
    int t = blockIdx.x, tid = threadIdx.x;
    for (int i = tid; i < H; i += 256) xs[i] = hs[(size_t)t * H + i];
    {
        int e = tid >> 3, part = tid & 7;
        const float* x = ri + (size_t)t * H + part * 128;
        const float* w = wr + (size_t)e * H + part * 128;
        float pa = 0.f;
        for (int i = 0; i < 128; ++i) pa += x[i] * w[i];
        for (int off = 1; off < 8; off <<= 1) pa += __shfl_xor(pa, off, 64);
        if (part == 0) lg[e] = pa;
    }
    __syncthreads();
    if (tid < E) out[(size_t)T * H + (size_t)t * E + tid] = lg[tid];
    if (tid == 0) {
        unsigned taken = 0; float val[KSEL];
        for (int k = 0; k < KSEL; ++k) {
            float best = -1e30f; int bi = 0;
            for (int i = 0; i < E; ++i)
                if (!((taken >> i) & 1u) && lg[i] > best) { best = lg[i]; bi = i; }
            taken |= 1u << bi; sel_e[k] = bi; val[k] = best;
        }
        float m = val[0], s = 0.f;
        for (int k = 0; k < KSEL; ++k) { sel_w[k] = __expf(val[k] - m); s += sel_w[k]; }
        for (int k = 0; k < KSEL; ++k) sel_w[k] /= s;
    }
    for (int i = tid; i < H; i += 256) obuf[i] = 0.f;
    __syncthreads();
    for (int k = 0; k < KSEL; ++k) {
        int e = sel_e[k]; float wk = sel_w[k];
        for (int f = tid; f < F; f += 256) {
            const float* pg = wg + (size_t)e * F * H + (size_t)f * H;
            const float* pu = wu + (size_t)e * F * H + (size_t)f * H;
            float g = 0, u = 0;
            for (int i = 0; i < H; ++i) { float x = xs[i]; g += x * pg[i]; u += x * pu[i]; }
            hbuf[f] = fmaxf(g, 0.f) * u;
        }
        __syncthreads();
        for (int n = tid; n < H; n += 256) {
            const float* pd = wd + (size_t)e * H * F + (size_t)n * F;
            float y = 0;
            for (int f = 0; f < F; ++f) y += hbuf[f] * pd[f];
            obuf[n] += y * wk;
        }
        __syncthreads();
    }
    for (int i = tid; i < H; i += 256) out[(size_t)t * H + i] = obuf[i];
}

extern "C" void kernel_launch(void* const* d_in, const int* in_sizes, int n_in,
                              void* d_out, int out_size, void* d_ws, size_t ws_size,
                              hipStream_t stream) {
    const float* ri = (const float*)d_in[0];
    const float* hs = (const float*)d_in[1];
    const float* wr = (const float*)d_in[2];
    const float* wg = (const float*)d_in[3];
    const float* wu = (const float*)d_in[4];
    const float* wd = (const float*)d_in[5];
    float* out = (float*)d_out;
    float* logits_out = out + (size_t)T * H;

    const size_t OFF_ENT = 1024;                               // counts: E*4 = 128 B
    const size_t NEED = OFF_ENT + (size_t)E * T * sizeof(uint2);  // + 512 KiB entries

    if (ws_size >= NEED) {
        int* counts = (int*)d_ws;
        uint2* entries = (uint2*)((char*)d_ws + OFF_ENT);
        hipMemsetAsync(counts, 0, E * sizeof(int), stream);
        hipMemsetAsync(out, 0, (size_t)T * H * sizeof(float), stream);
        k_router<<<T, 64, 0, stream>>>(ri, wr, logits_out, counts, entries);
        dim3 grid(E, T / TM);
        k_expert<<<grid, 256, 0, stream>>>(hs, wg, wu, wd, counts, entries, out);
    } else {
        k_fallback<<<T, 256, 0, stream>>>(ri, hs, wr, wg, wu, wd, out);
    }
}

// Round 4
// 449.649 us; speedup vs baseline: 9.5692x; 9.5692x over previous
//
#include <hip/hip_runtime.h>
#include <hip/hip_bf16.h>
#include <stdint.h>

#define T 2048
#define H 1024
#define F 512
#define E 32
#define KSEL 4
#define TM 16

typedef __hip_bfloat16 bf16;
typedef short frag8 __attribute__((ext_vector_type(8)));
typedef float f32x4 __attribute__((ext_vector_type(4)));

union V8 { uint4 u4; unsigned short s[8]; };

__device__ __forceinline__ float b2f(unsigned short u) {
    union { unsigned u32; float f; } c; c.u32 = ((unsigned)u) << 16; return c.f;
}
__device__ __forceinline__ unsigned short f2b(float f) {
    bf16 b = __float2bfloat16(f);
    return *reinterpret_cast<unsigned short*>(&b);
}
__device__ __forceinline__ uint2 pack4(float4 v) {
    uint2 r;
    r.x = (unsigned)f2b(v.x) | ((unsigned)f2b(v.y) << 16);
    r.y = (unsigned)f2b(v.z) | ((unsigned)f2b(v.w) << 16);
    return r;
}
__device__ __forceinline__ void ld8f(const float* __restrict__ p, int k, float* o) {
    float4 a = *(const float4*)(p + k);
    float4 b = *(const float4*)(p + k + 4);
    o[0] = a.x; o[1] = a.y; o[2] = a.z; o[3] = a.w;
    o[4] = b.x; o[5] = b.y; o[6] = b.z; o[7] = b.w;
}

// ---------------- Router ----------------
__global__ __launch_bounds__(64) void k_router(const float* __restrict__ ri,
                                               const float* __restrict__ wr,
                                               float* __restrict__ logits_out,
                                               int* __restrict__ counts,
                                               uint2* __restrict__ entries) {
    __shared__ float lg[E];
    int t = blockIdx.x;
    int lane = threadIdx.x;
    int e = lane >> 1, half = lane & 1;
    const float4* x = (const float4*)(ri + (size_t)t * H + half * 512);
    const float4* w = (const float4*)(wr + (size_t)e * H + half * 512);
    float acc = 0.f;
    for (int i = 0; i < 128; ++i) {
        float4 xv = x[i], wv = w[i];
        acc += xv.x * wv.x + xv.y * wv.y + xv.z * wv.z + xv.w * wv.w;
    }
    acc += __shfl_xor(acc, 1, 64);
    if (half == 0) lg[e] = acc;
    __syncthreads();
    if (lane < E) logits_out[(size_t)t * E + lane] = lg[lane];
    if (lane == 0) {
        int sel[KSEL]; float val[KSEL];
        unsigned taken = 0;
        for (int k = 0; k < KSEL; ++k) {
            float best = -1e30f; int bi = 0;
            for (int i = 0; i < E; ++i)
                if (!((taken >> i) & 1u) && lg[i] > best) { best = lg[i]; bi = i; }
            taken |= 1u << bi; sel[k] = bi; val[k] = best;
        }
        float m = val[0], s = 0.f, w4[KSEL];
        for (int k = 0; k < KSEL; ++k) { w4[k] = __expf(val[k] - m); s += w4[k]; }
        float inv = 1.f / s;
        for (int k = 0; k < KSEL; ++k) {
            int pos = atomicAdd(&counts[sel[k]], 1);
            uint2 ent; ent.x = (unsigned)t; ent.y = __float_as_uint(w4[k] * inv);
            entries[(size_t)sel[k] * T + pos] = ent;
        }
    }
}

// ---------------- Prefix offsets over expert counts ----------------
__global__ __launch_bounds__(64) void k_offsets(const int* __restrict__ counts,
                                                int* __restrict__ off) {
    if (threadIdx.x == 0) {
        int s = 0;
        for (int e = 0; e < E; ++e) { off[e] = s; s += counts[e]; }
    }
}

// ---------------- Phase 1 MFMA: H1 = relu(X Wg^T) * (X Wu^T) ----------------
// grid (E, T/64, F/64), block 256. Wave (wr,wc) computes 32x32 of G and U.
__global__ __launch_bounds__(256) void k_gemm1(const float* __restrict__ hs,
                                               const float* __restrict__ wg,
                                               const float* __restrict__ wu,
                                               const int* __restrict__ counts,
                                               const int* __restrict__ off,
                                               const uint2* __restrict__ entries,
                                               unsigned short* __restrict__ h1) {
    int e = blockIdx.x, mt = blockIdx.y, nt = blockIdx.z;
    int cnt = counts[e];
    int base = mt * 64;
    if (base >= cnt) return;
    int rows = min(64, cnt - base);
    int slot0 = off[e] + base;

    __shared__ unsigned short Xs[64][72];
    __shared__ unsigned short Ag[64][72];
    __shared__ unsigned short Au[64][72];
    __shared__ int tok_s[64];

    int tid = threadIdx.x;
    if (tid < 64)
        tok_s[tid] = (int)entries[(size_t)e * T + base + min(tid, rows - 1)].x;
    __syncthreads();

    int rloc = tid >> 4;          // 0..15 (row within 16-row group)
    int c4 = (tid & 15) * 4;      // element column of this thread's float4
    int f0 = nt * 64;
    const size_t wgb = (size_t)e * F * H + (size_t)f0 * H;

    f32x4 accG[2][2], accU[2][2];
#pragma unroll
    for (int i = 0; i < 2; ++i)
#pragma unroll
        for (int j = 0; j < 2; ++j) {
            accG[i][j] = (f32x4){0.f, 0.f, 0.f, 0.f};
            accU[i][j] = (f32x4){0.f, 0.f, 0.f, 0.f};
        }

    int l = tid & 63, w = tid >> 6;
    int wr = w & 1, wc = w >> 1;
    int mn = l & 15, quad = l >> 4;

    for (int kc = 0; kc < H / 64; ++kc) {
        int k0 = kc * 64;
        __syncthreads();
#pragma unroll
        for (int g = 0; g < 4; ++g) {
            int r = g * 16 + rloc;
            float4 xv = *(const float4*)(hs + (size_t)tok_s[r] * H + k0 + c4);
            *(uint2*)&Xs[r][c4] = pack4(xv);
            float4 gv = *(const float4*)(wg + wgb + (size_t)r * H + k0 + c4);
            *(uint2*)&Ag[r][c4] = pack4(gv);
            float4 uv = *(const float4*)(wu + wgb + (size_t)r * H + k0 + c4);
            *(uint2*)&Au[r][c4] = pack4(uv);
        }
        __syncthreads();
#pragma unroll
        for (int s = 0; s < 2; ++s) {
            int kk = s * 32 + quad * 8;
            frag8 a0 = *(const frag8*)&Xs[wr * 32 + mn][kk];
            frag8 a1 = *(const frag8*)&Xs[wr * 32 + 16 + mn][kk];
            frag8 g0 = *(const frag8*)&Ag[wc * 32 + mn][kk];
            frag8 g1 = *(const frag8*)&Ag[wc * 32 + 16 + mn][kk];
            frag8 u0 = *(const frag8*)&Au[wc * 32 + mn][kk];
            frag8 u1 = *(const frag8*)&Au[wc * 32 + 16 + mn][kk];
            accG[0][0] = __builtin_amdgcn_mfma_f32_16x16x32_bf16(a0, g0, accG[0][0], 0, 0, 0);
            accG[0][1] = __builtin_amdgcn_mfma_f32_16x16x32_bf16(a0, g1, accG[0][1], 0, 0, 0);
            accG[1][0] = __builtin_amdgcn_mfma_f32_16x16x32_bf16(a1, g0, accG[1][0], 0, 0, 0);
            accG[1][1] = __builtin_amdgcn_mfma_f32_16x16x32_bf16(a1, g1, accG[1][1], 0, 0, 0);
            accU[0][0] = __builtin_amdgcn_mfma_f32_16x16x32_bf16(a0, u0, accU[0][0], 0, 0, 0);
            accU[0][1] = __builtin_amdgcn_mfma_f32_16x16x32_bf16(a0, u1, accU[0][1], 0, 0, 0);
            accU[1][0] = __builtin_amdgcn_mfma_f32_16x16x32_bf16(a1, u0, accU[1][0], 0, 0, 0);
            accU[1][1] = __builtin_amdgcn_mfma_f32_16x16x32_bf16(a1, u1, accU[1][1], 0, 0, 0);
        }
    }
    // epilogue: h1 = relu(G)*U (bf16)
#pragma unroll
    for (int i = 0; i < 2; ++i)
#pragma unroll
        for (int j = 0; j < 2; ++j) {
#pragma unroll
            for (int r = 0; r < 4; ++r) {
                int mrow = wr * 32 + i * 16 + quad * 4 + r;
                if (mrow < rows) {
                    float gvv = accG[i][j][r], uvv = accU[i][j][r];
                    h1[(size_t)(slot0 + mrow) * F + f0 + wc * 32 + j * 16 + mn] =
                        f2b(fmaxf(gvv, 0.f) * uvv);
                }
            }
        }
}

// ---------------- Phase 2 MFMA: out += wgt * (H1 Wd^T) ----------------
// grid (E, T/64, H/64), block 256.
__global__ __launch_bounds__(256) void k_gemm2(const unsigned short* __restrict__ h1,
                                               const float* __restrict__ wd,
                                               const int* __restrict__ counts,
                                               const int* __restrict__ off,
                                               const uint2* __restrict__ entries,
                                               float* __restrict__ out) {
    int e = blockIdx.x, mt = blockIdx.y, nt = blockIdx.z;
    int cnt = counts[e];
    int base = mt * 64;
    if (base >= cnt) return;
    int rows = min(64, cnt - base);
    int slot0 = off[e] + base;

    __shared__ unsigned short Hs[64][72];
    __shared__ unsigned short Ds[64][72];
    __shared__ int tok_s[64];
    __shared__ float wgt_s[64];

    int tid = threadIdx.x;
    if (tid < 64) {
        uint2 ent = entries[(size_t)e * T + base + min(tid, rows - 1)];
        tok_s[tid] = (int)ent.x;
        wgt_s[tid] = (tid < rows) ? __uint_as_float(ent.y) : 0.f;
    }
    __syncthreads();

    int rloc = tid >> 4;
    int c4 = (tid & 15) * 4;
    int n0 = nt * 64;
    const size_t wdb = (size_t)e * H * F + (size_t)n0 * F;

    f32x4 accY[2][2];
#pragma unroll
    for (int i = 0; i < 2; ++i)
#pragma unroll
        for (int j = 0; j < 2; ++j) accY[i][j] = (f32x4){0.f, 0.f, 0.f, 0.f};

    int l = tid & 63, w = tid >> 6;
    int wr = w & 1, wc = w >> 1;
    int mn = l & 15, quad = l >> 4;

    for (int kc = 0; kc < F / 64; ++kc) {
        int k0 = kc * 64;
        __syncthreads();
#pragma unroll
        for (int g = 0; g < 4; ++g) {
            int r = g * 16 + rloc;
            int hrow = slot0 + min(r, rows - 1);
            *(uint2*)&Hs[r][c4] = *(const uint2*)(h1 + (size_t)hrow * F + k0 + c4);
            float4 dv = *(const float4*)(wd + wdb + (size_t)r * F + k0 + c4);
            *(uint2*)&Ds[r][c4] = pack4(dv);
        }
        __syncthreads();
#pragma unroll
        for (int s = 0; s < 2; ++s) {
            int kk = s * 32 + quad * 8;
            frag8 a0 = *(const frag8*)&Hs[wr * 32 + mn][kk];
            frag8 a1 = *(const frag8*)&Hs[wr * 32 + 16 + mn][kk];
            frag8 b0 = *(const frag8*)&Ds[wc * 32 + mn][kk];
            frag8 b1 = *(const frag8*)&Ds[wc * 32 + 16 + mn][kk];
            accY[0][0] = __builtin_amdgcn_mfma_f32_16x16x32_bf16(a0, b0, accY[0][0], 0, 0, 0);
            accY[0][1] = __builtin_amdgcn_mfma_f32_16x16x32_bf16(a0, b1, accY[0][1], 0, 0, 0);
            accY[1][0] = __builtin_amdgcn_mfma_f32_16x16x32_bf16(a1, b0, accY[1][0], 0, 0, 0);
            accY[1][1] = __builtin_amdgcn_mfma_f32_16x16x32_bf16(a1, b1, accY[1][1], 0, 0, 0);
        }
    }
#pragma unroll
    for (int i = 0; i < 2; ++i)
#pragma unroll
        for (int j = 0; j < 2; ++j) {
#pragma unroll
            for (int r = 0; r < 4; ++r) {
                int mrow = wr * 32 + i * 16 + quad * 4 + r;
                if (mrow < rows) {
                    float y = accY[i][j][r] * wgt_s[mrow];
                    atomicAdd(out + (size_t)tok_s[mrow] * H + n0 + wc * 32 + j * 16 + mn, y);
                }
            }
        }
}

// ---------------- Round-3 VALU expert path (middle ws tier, known-good) ----------------
__global__ __launch_bounds__(256) void k_expert(const float* __restrict__ hs,
                                                const float* __restrict__ wg,
                                                const float* __restrict__ wu,
                                                const float* __restrict__ wd,
                                                const int* __restrict__ counts,
                                                const uint2* __restrict__ entries,
                                                float* __restrict__ out) {
    int e = blockIdx.x;
    int tile = blockIdx.y;
    int n_tok = counts[e];
    int base = tile * TM;
    if (base >= n_tok) return;
    int rows = min(TM, n_tok - base);

    __shared__ unsigned short Xs[TM][H + 8];
    __shared__ unsigned short H1s[TM][F + 8];
    __shared__ int tok_s[TM];
    __shared__ float wgt_s[TM];

    int tid = threadIdx.x;
    if (tid < TM) {
        uint2 ent = entries[(size_t)e * T + base + min(tid, rows - 1)];
        tok_s[tid] = (int)ent.x;
        wgt_s[tid] = (tid < rows) ? __uint_as_float(ent.y) : 0.f;
    }
    __syncthreads();
    {
        int m = tid >> 4, part = tid & 15;
        const float* src = hs + (size_t)tok_s[m] * H + part * 64;
#pragma unroll
        for (int j = 0; j < 8; ++j) {
            float4 v0 = *(const float4*)(src + j * 8);
            float4 v1 = *(const float4*)(src + j * 8 + 4);
            V8 o;
            o.s[0] = f2b(v0.x); o.s[1] = f2b(v0.y); o.s[2] = f2b(v0.z); o.s[3] = f2b(v0.w);
            o.s[4] = f2b(v1.x); o.s[5] = f2b(v1.y); o.s[6] = f2b(v1.z); o.s[7] = f2b(v1.w);
            *(uint4*)&Xs[m][part * 64 + j * 8] = o.u4;
        }
    }
    __syncthreads();

    int mg = tid >> 5, fg = tid & 31;
    int m0 = mg * 2, m1 = m0 + 1;

    for (int ft = 0; ft < F / 64; ++ft) {
        int f0 = ft * 64 + fg * 2;
        const float* pg0 = wg + (size_t)e * F * H + (size_t)f0 * H;
        const float* pg1 = pg0 + H;
        const float* pu0 = wu + (size_t)e * F * H + (size_t)f0 * H;
        const float* pu1 = pu0 + H;
        float g0 = 0, g1 = 0, g2 = 0, g3 = 0, u0 = 0, u1 = 0, u2 = 0, u3 = 0;
        for (int k = 0; k < H; k += 8) {
            V8 xa, xb;
            xa.u4 = *(const uint4*)&Xs[m0][k];
            xb.u4 = *(const uint4*)&Xs[m1][k];
            float A0[8], A1[8], U0[8], U1[8];
            ld8f(pg0, k, A0); ld8f(pg1, k, A1);
            ld8f(pu0, k, U0); ld8f(pu1, k, U1);
#pragma unroll
            for (int j = 0; j < 8; ++j) {
                float xj0 = b2f(xa.s[j]), xj1 = b2f(xb.s[j]);
                g0 += xj0 * A0[j]; g1 += xj0 * A1[j]; g2 += xj1 * A0[j]; g3 += xj1 * A1[j];
                u0 += xj0 * U0[j]; u1 += xj0 * U1[j]; u2 += xj1 * U0[j]; u3 += xj1 * U1[j];
            }
        }
        H1s[m0][f0]     = f2b(fmaxf(g0, 0.f) * u0);
        H1s[m0][f0 + 1] = f2b(fmaxf(g1, 0.f) * u1);
        H1s[m1][f0]     = f2b(fmaxf(g2, 0.f) * u2);
        H1s[m1][f0 + 1] = f2b(fmaxf(g3, 0.f) * u3);
    }
    __syncthreads();

    float wm0 = wgt_s[m0], wm1 = wgt_s[m1];
    for (int nt = 0; nt < H / 64; ++nt) {
        int n0 = nt * 64 + fg * 2;
        const float* pd0 = wd + (size_t)e * H * F + (size_t)n0 * F;
        const float* pd1 = pd0 + F;
        float y00 = 0, y01 = 0, y10 = 0, y11 = 0;
        for (int f = 0; f < F; f += 8) {
            V8 ha, hb;
            ha.u4 = *(const uint4*)&H1s[m0][f];
            hb.u4 = *(const uint4*)&H1s[m1][f];
            float D0[8], D1[8];
            ld8f(pd0, f, D0); ld8f(pd1, f, D1);
#pragma unroll
            for (int j = 0; j < 8; ++j) {
                float h0 = b2f(ha.s[j]), h1v = b2f(hb.s[j]);
                y00 += h0 * D0[j]; y01 += h0 * D1[j]; y10 += h1v * D0[j]; y11 += h1v * D1[j];
            }
        }
        if (m0 < rows) {
            float* p = out + (size_t)tok_s[m0] * H + n0;
            atomicAdd(p, y00 * wm0); atomicAdd(p + 1, y01 * wm0);
        }
        if (m1 < rows) {
            float* p = out + (size_t)tok_s[m1] * H + n0;
            atomicAdd(p, y10 * wm1); atomicAdd(p + 1, y11 * wm1);
        }
    }
}

// ---------------- Fallback (tiny ws) ----------------
__global__ __launch_bounds__(256) void k_fallback(const float* __restrict__ ri,
                                                  const float* __restrict__ hs,
                                                  const float* __restrict__ wr,
                                                  const float* __restrict__ wg,
                                                  const float* __restrict__ wu,
                                                  const float* __restrict__ wd,
                                                  float* __restrict__ out) {
    __shared__ float lg[E];
    __shared__ float xs[H];
    __shared__ float hbuf[F];
    __shared__ float obuf[H];
    __shared__ float sel_w[KSEL];
    __shared__ int sel_e[KSEL];
    int t = blockIdx.x, tid = threadIdx.x;
    for (int i = tid; i < H; i += 256) xs[i] = hs[(size_t)t * H + i];
    {
        int e = tid >> 3, part = tid & 7;
        const float* x = ri + (size_t)t * H + part * 128;
        const float* w = wr + (size_t)e * H + part * 128;
        float pa = 0.f;
        for (int i = 0; i < 128; ++i) pa += x[i] * w[i];
        for (int off = 1; off < 8; off <<= 1) pa += __shfl_xor(pa, off, 64);
        if (part == 0) lg[e] = pa;
    }
    __syncthreads();
    if (tid < E) out[(size_t)T * H + (size_t)t * E + tid] = lg[tid];
    if (tid == 0) {
        unsigned taken = 0; float val[KSEL];
        for (int k = 0; k < KSEL; ++k) {
            float best = -1e30f; int bi = 0;
            for (int i = 0; i < E; ++i)
                if (!((taken >> i) & 1u) && lg[i] > best) { best = lg[i]; bi = i; }
            taken |= 1u << bi; sel_e[k] = bi; val[k] = best;
        }
        float m = val[0], s = 0.f;
        for (int k = 0; k < KSEL; ++k) { sel_w[k] = __expf(val[k] - m); s += sel_w[k]; }
        for (int k = 0; k < KSEL; ++k) sel_w[k] /= s;
    }
    for (int i = tid; i < H; i += 256) obuf[i] = 0.f;
    __syncthreads();
    for (int k = 0; k < KSEL; ++k) {
        int e = sel_e[k]; float wk = sel_w[k];
        for (int f = tid; f < F; f += 256) {
            const float* pg = wg + (size_t)e * F * H + (size_t)f * H;
            const float* pu = wu + (size_t)e * F * H + (size_t)f * H;
            float g = 0, u = 0;
            for (int i = 0; i < H; ++i) { float x = xs[i]; g += x * pg[i]; u += x * pu[i]; }
            hbuf[f] = fmaxf(g, 0.f) * u;
        }
        __syncthreads();
        for (int n = tid; n < H; n += 256) {
            const float* pd = wd + (size_t)e * H * F + (size_t)n * F;
            float y = 0;
            for (int f = 0; f < F; ++f) y += hbuf[f] * pd[f];
            obuf[n] += y * wk;
        }
        __syncthreads();
    }
    for (int i = tid; i < H; i += 256) out[(size_t)t * H + i] = obuf[i];
}

extern "C" void kernel_launch(void* const* d_in, const int* in_sizes, int n_in,
                              void* d_out, int out_size, void* d_ws, size_t ws_size,
                              hipStream_t stream) {
    const float* ri = (const float*)d_in[0];
    const float* hs = (const float*)d_in[1];
    const float* wr = (const float*)d_in[2];
    const float* wg = (const float*)d_in[3];
    const float* wu = (const float*)d_in[4];
    const float* wd = (const float*)d_in[5];
    float* out = (float*)d_out;
    float* logits_out = out + (size_t)T * H;

    const size_t OFF_OFFS = 512;
    const size_t OFF_ENT = 4096;                              // E*T*8 = 512 KiB
    const size_t OFF_H1 = (size_t)1 << 20;                    // 1 MiB
    const size_t H1_BYTES = (size_t)T * KSEL * F * 2;         // 8 MiB bf16
    const size_t NEED_MFMA = OFF_H1 + H1_BYTES + 65536;
    const size_t NEED_MID = OFF_ENT + (size_t)E * T * sizeof(uint2);

    if (ws_size >= NEED_MFMA) {
        int* counts = (int*)d_ws;
        int* offs = (int*)((char*)d_ws + OFF_OFFS);
        uint2* entries = (uint2*)((char*)d_ws + OFF_ENT);
        unsigned short* h1 = (unsigned short*)((char*)d_ws + OFF_H1);
        hipMemsetAsync(counts, 0, E * sizeof(int), stream);
        hipMemsetAsync(out, 0, (size_t)T * H * sizeof(float), stream);
        k_router<<<T, 64, 0, stream>>>(ri, wr, logits_out, counts, entries);
        k_offsets<<<1, 64, 0, stream>>>(counts, offs);
        k_gemm1<<<dim3(E, T / 64, F / 64), 256, 0, stream>>>(hs, wg, wu, counts, offs, entries, h1);
        k_gemm2<<<dim3(E, T / 64, H / 64), 256, 0, stream>>>(h1, wd, counts, offs, entries, out);
    } else if (ws_size >= NEED_MID) {
        int* counts = (int*)d_ws;
        uint2* entries = (uint2*)((char*)d_ws + OFF_ENT);
        hipMemsetAsync(counts, 0, E * sizeof(int), stream);
        hipMemsetAsync(out, 0, (size_t)T * H * sizeof(float), stream);
        k_router<<<T, 64, 0, stream>>>(ri, wr, logits_out, counts, entries);
        dim3 grid(E, T / TM);
        k_expert<<<grid, 256, 0, stream>>>(hs, wg, wu, wd, counts, entries, out);
    } else {
        k_fallback<<<T, 256, 0, stream>>>(ri, hs, wr, wg, wu, wd, out);
    }
}